// Round 4
// baseline (54.458 us; speedup 1.0000x reference)
//
#include <hip/hip_runtime.h>

// QuantumAttention: out[b,s,e] = sum_q q[b,s,q] * W_dec[e,q] + x[b,s,e]
//   angles = x @ W_enc^T, c = cos(angles)
//   q[0] = prod(c[1..7]); q[i] = prod(c[0..i])
//
// R4: (1) packed-f32 math (v_pk_fma_f32 via __builtin_elementwise_fma on
// float2) for encode/decode — ~20% VALU cut; (2) persistent blocks
// (grid 2048, 2 iters x T=4) with cross-iteration x prefetch so HBM
// latency hides under the previous iteration's reduce/epilogue.

typedef float v2f __attribute__((ext_vector_type(2)));

#define EDIM 1024
#define QDIM 8
#define NTOK 16384
#define BLOCK 256
#define T 4
#define GRID 2048
#define ITERS (NTOK / (GRID * T))   // 2

// v += dpp_move(v); bound_ctrl=true -> out-of-range lanes contribute 0
template<int CTRL>
__device__ __forceinline__ float dpp_add(float v) {
    int m = __builtin_amdgcn_update_dpp(0, __float_as_int(v), CTRL, 0xF, 0xF, true);
    return v + __int_as_float(m);
}

// 64-lane sum on the VALU pipe; result valid in lane 63 only.
__device__ __forceinline__ float wave_sum63(float v) {
    v = dpp_add<0x111>(v);   // row_shr:1
    v = dpp_add<0x112>(v);   // row_shr:2
    v = dpp_add<0x114>(v);   // row_shr:4
    v = dpp_add<0x118>(v);   // row_shr:8
    v = dpp_add<0x142>(v);   // row_bcast:15
    v = dpp_add<0x143>(v);   // row_bcast:31
    return v;
}

__global__ __launch_bounds__(BLOCK, 4)
void qattn_kernel(const float* __restrict__ x,
                  const float* __restrict__ W_enc,   // [Q][E]
                  const float* __restrict__ W_dec,   // [E][Q]
                  float* __restrict__ out)
{
    __shared__ float red[ITERS][T][4][QDIM];   // per-iter slot: no extra barrier

    const int t    = threadIdx.x;
    const int lane = t & 63;
    const int wave = t >> 6;
    const int e0   = t * 4;

    // ---- encode weights as e-pairs: wenc2[q][k] = {W[q][e0+2k], W[q][e0+2k+1]} ----
    v2f wenc2[QDIM][2];
#pragma unroll
    for (int q = 0; q < QDIM; ++q) {
        float4 w = *(const float4*)(W_enc + q * EDIM + e0);
        wenc2[q][0] = (v2f){w.x, w.y};
        wenc2[q][1] = (v2f){w.z, w.w};
    }
    // ---- decode weights as q-pairs: wdec2[j][k] = {W_dec[e0+j][2k], W_dec[e0+j][2k+1]} ----
    v2f wdec2[4][4];
#pragma unroll
    for (int j = 0; j < 4; ++j) {
        float4 a = *(const float4*)(W_dec + (e0 + j) * QDIM);
        float4 b = *(const float4*)(W_dec + (e0 + j) * QDIM + 4);
        wdec2[j][0] = (v2f){a.x, a.y};
        wdec2[j][1] = (v2f){a.z, a.w};
        wdec2[j][2] = (v2f){b.x, b.y};
        wdec2[j][3] = (v2f){b.z, b.w};
    }

    const int tok0 = blockIdx.x * (T * ITERS);

    float4 xv[T];
#pragma unroll
    for (int i = 0; i < T; ++i)
        xv[i] = *(const float4*)(x + (size_t)(tok0 + i) * EDIM + e0);

#pragma unroll
    for (int it = 0; it < ITERS; ++it) {
        // prefetch next iteration's x before any compute of this iteration
        float4 xn[T];
        if (it + 1 < ITERS) {
#pragma unroll
            for (int i = 0; i < T; ++i)
                xn[i] = *(const float4*)(x + (size_t)(tok0 + (it + 1) * T + i) * EDIM + e0);
        }

        // ---- encode: packed dot4 (2 pk_fma + 1 h-add per q) ----
        float ang[T][QDIM];
#pragma unroll
        for (int i = 0; i < T; ++i) {
            v2f x01 = (v2f){xv[i].x, xv[i].y};
            v2f x23 = (v2f){xv[i].z, xv[i].w};
#pragma unroll
            for (int q = 0; q < QDIM; ++q) {
                v2f acc = x01 * wenc2[q][0];
                acc = __builtin_elementwise_fma(x23, wenc2[q][1], acc);
                ang[i][q] = acc.x + acc.y;
            }
        }

        // ---- 64-lane DPP reduce (VALU pipe), sum lands in lane 63 ----
#pragma unroll
        for (int i = 0; i < T; ++i)
#pragma unroll
            for (int q = 0; q < QDIM; ++q)
                ang[i][q] = wave_sum63(ang[i][q]);

        // ---- cross-wave combine ----
        if (lane == 63) {
#pragma unroll
            for (int i = 0; i < T; ++i) {
                *(float4*)&red[it][i][wave][0] =
                    make_float4(ang[i][0], ang[i][1], ang[i][2], ang[i][3]);
                *(float4*)&red[it][i][wave][4] =
                    make_float4(ang[i][4], ang[i][5], ang[i][6], ang[i][7]);
            }
        }
        __syncthreads();

#pragma unroll
        for (int i = 0; i < T; ++i) {
            float4 lo = make_float4(0.f, 0.f, 0.f, 0.f);
            float4 hi = make_float4(0.f, 0.f, 0.f, 0.f);
#pragma unroll
            for (int w = 0; w < 4; ++w) {
                float4 a = *(const float4*)&red[it][i][w][0];
                float4 b = *(const float4*)&red[it][i][w][4];
                lo.x += a.x; lo.y += a.y; lo.z += a.z; lo.w += a.w;
                hi.x += b.x; hi.y += b.y; hi.z += b.z; hi.w += b.w;
            }
            float c[QDIM];
            c[0] = __cosf(lo.x); c[1] = __cosf(lo.y);
            c[2] = __cosf(lo.z); c[3] = __cosf(lo.w);
            c[4] = __cosf(hi.x); c[5] = __cosf(hi.y);
            c[6] = __cosf(hi.z); c[7] = __cosf(hi.w);

            float qv[QDIM];
            float q0 = c[1];
#pragma unroll
            for (int q = 2; q < QDIM; ++q) q0 *= c[q];
            qv[0] = q0;
            float p = c[0];
#pragma unroll
            for (int q = 1; q < QDIM; ++q) { p *= c[q]; qv[q] = p; }

            v2f qp[4];
            qp[0] = (v2f){qv[0], qv[1]};
            qp[1] = (v2f){qv[2], qv[3]};
            qp[2] = (v2f){qv[4], qv[5]};
            qp[3] = (v2f){qv[6], qv[7]};

            // ---- decode (packed over q-pairs) + residual ----
            float oacc[4];
            oacc[0] = xv[i].x; oacc[1] = xv[i].y;
            oacc[2] = xv[i].z; oacc[3] = xv[i].w;
#pragma unroll
            for (int j = 0; j < 4; ++j) {
                v2f a = qp[0] * wdec2[j][0];
                a = __builtin_elementwise_fma(qp[1], wdec2[j][1], a);
                a = __builtin_elementwise_fma(qp[2], wdec2[j][2], a);
                a = __builtin_elementwise_fma(qp[3], wdec2[j][3], a);
                oacc[j] += a.x + a.y;
            }
            *(float4*)(out + (size_t)(tok0 + it * T + i) * EDIM + e0) =
                make_float4(oacc[0], oacc[1], oacc[2], oacc[3]);
        }

        if (it + 1 < ITERS) {
#pragma unroll
            for (int i = 0; i < T; ++i) xv[i] = xn[i];
        }
    }
}

extern "C" void kernel_launch(void* const* d_in, const int* in_sizes, int n_in,
                              void* d_out, int out_size, void* d_ws, size_t ws_size,
                              hipStream_t stream) {
    const float* x     = (const float*)d_in[0];
    const float* W_enc = (const float*)d_in[1];
    const float* W_dec = (const float*)d_in[2];
    float* out         = (float*)d_out;

    hipLaunchKernelGGL(qattn_kernel, dim3(GRID), dim3(BLOCK), 0, stream,
                       x, W_enc, W_dec, out);
}

// Round 6
// 31.009 us; speedup vs baseline: 1.7562x; 1.7562x over previous
//
#include <hip/hip_runtime.h>

// QuantumAttention: out[b,s,e] = sum_q q[b,s,q] * W_dec[e,q] + x[b,s,e]
//   angles = x @ W_enc^T, c = cos(angles)
//   q[0] = prod(c[1..7]); q[i] = prod(c[0..i])
//
// R6 = R5 with the compile fix: nontemporal store needs a clang
// ext_vector_type, not HIP's float4 struct.
// Structure: persistent+prefetch, T=2 tokens/iter, ITERS=4, grid 2048,
// launch_bounds(256,2) to avoid R4's spill (WRITE_SIZE 65->150MB).
// Packed f32 math (v_pk_fma_f32); DPP wave reduce; nontemporal out stores.

typedef float v2f __attribute__((ext_vector_type(2)));
typedef float v4f __attribute__((ext_vector_type(4)));

#define EDIM 1024
#define QDIM 8
#define NTOK 16384
#define BLOCK 256
#define T 2
#define ITERS 4
#define GRID (NTOK / (T * ITERS))   // 2048

// v += dpp_move(v); bound_ctrl=true -> out-of-range lanes contribute 0
template<int CTRL>
__device__ __forceinline__ float dpp_add(float v) {
    int m = __builtin_amdgcn_update_dpp(0, __float_as_int(v), CTRL, 0xF, 0xF, true);
    return v + __int_as_float(m);
}

// 64-lane sum on the VALU pipe; result valid in lane 63 only.
__device__ __forceinline__ float wave_sum63(float v) {
    v = dpp_add<0x111>(v);   // row_shr:1
    v = dpp_add<0x112>(v);   // row_shr:2
    v = dpp_add<0x114>(v);   // row_shr:4
    v = dpp_add<0x118>(v);   // row_shr:8
    v = dpp_add<0x142>(v);   // row_bcast:15
    v = dpp_add<0x143>(v);   // row_bcast:31
    return v;
}

__global__ __launch_bounds__(BLOCK, 2)
void qattn_kernel(const float* __restrict__ x,
                  const float* __restrict__ W_enc,   // [Q][E]
                  const float* __restrict__ W_dec,   // [E][Q]
                  float* __restrict__ out)
{
    __shared__ float red[ITERS][T][4][QDIM];   // own slot per iter: 1 barrier/iter

    const int t    = threadIdx.x;
    const int lane = t & 63;
    const int wave = t >> 6;
    const int e0   = t * 4;

    // ---- encode weights as e-pairs ----
    v2f wenc2[QDIM][2];
#pragma unroll
    for (int q = 0; q < QDIM; ++q) {
        v4f w = *(const v4f*)(W_enc + q * EDIM + e0);
        wenc2[q][0] = (v2f){w.x, w.y};
        wenc2[q][1] = (v2f){w.z, w.w};
    }
    // ---- decode weights as q-pairs ----
    v2f wdec2[4][4];
#pragma unroll
    for (int j = 0; j < 4; ++j) {
        v4f a = *(const v4f*)(W_dec + (e0 + j) * QDIM);
        v4f b = *(const v4f*)(W_dec + (e0 + j) * QDIM + 4);
        wdec2[j][0] = (v2f){a.x, a.y};
        wdec2[j][1] = (v2f){a.z, a.w};
        wdec2[j][2] = (v2f){b.x, b.y};
        wdec2[j][3] = (v2f){b.z, b.w};
    }

    const int tok0 = blockIdx.x * (T * ITERS);

    v4f xv[T];
#pragma unroll
    for (int i = 0; i < T; ++i)
        xv[i] = *(const v4f*)(x + (size_t)(tok0 + i) * EDIM + e0);

#pragma unroll
    for (int it = 0; it < ITERS; ++it) {
        // prefetch next iteration's x before any compute of this iteration
        v4f xn[T];
        if (it + 1 < ITERS) {
#pragma unroll
            for (int i = 0; i < T; ++i)
                xn[i] = *(const v4f*)(x + (size_t)(tok0 + (it + 1) * T + i) * EDIM + e0);
        }

        // ---- encode: packed dot4 (pk_mul + pk_fma + hadd per q) ----
        float ang[T][QDIM];
#pragma unroll
        for (int i = 0; i < T; ++i) {
            v2f x01 = (v2f){xv[i].x, xv[i].y};
            v2f x23 = (v2f){xv[i].z, xv[i].w};
#pragma unroll
            for (int q = 0; q < QDIM; ++q) {
                v2f acc = x01 * wenc2[q][0];
                acc = __builtin_elementwise_fma(x23, wenc2[q][1], acc);
                ang[i][q] = acc.x + acc.y;
            }
        }

        // ---- 64-lane DPP reduce (VALU pipe), sum lands in lane 63 ----
#pragma unroll
        for (int i = 0; i < T; ++i)
#pragma unroll
            for (int q = 0; q < QDIM; ++q)
                ang[i][q] = wave_sum63(ang[i][q]);

        // ---- cross-wave combine: lane 63 publishes, one barrier ----
        if (lane == 63) {
#pragma unroll
            for (int i = 0; i < T; ++i) {
                *(v4f*)&red[it][i][wave][0] = (v4f){ang[i][0], ang[i][1], ang[i][2], ang[i][3]};
                *(v4f*)&red[it][i][wave][4] = (v4f){ang[i][4], ang[i][5], ang[i][6], ang[i][7]};
            }
        }
        __syncthreads();

#pragma unroll
        for (int i = 0; i < T; ++i) {
            // sum 4 wave partials with packed adds (broadcast LDS reads)
            v2f s01 = (v2f){0.f, 0.f}, s23 = (v2f){0.f, 0.f};
            v2f s45 = (v2f){0.f, 0.f}, s67 = (v2f){0.f, 0.f};
#pragma unroll
            for (int w = 0; w < 4; ++w) {
                v4f a = *(const v4f*)&red[it][i][w][0];
                v4f b = *(const v4f*)&red[it][i][w][4];
                s01 += (v2f){a.x, a.y};
                s23 += (v2f){a.z, a.w};
                s45 += (v2f){b.x, b.y};
                s67 += (v2f){b.z, b.w};
            }
            float c[QDIM];
            c[0] = __cosf(s01.x); c[1] = __cosf(s01.y);
            c[2] = __cosf(s23.x); c[3] = __cosf(s23.y);
            c[4] = __cosf(s45.x); c[5] = __cosf(s45.y);
            c[6] = __cosf(s67.x); c[7] = __cosf(s67.y);

            float qv[QDIM];
            float q0 = c[1];
#pragma unroll
            for (int q = 2; q < QDIM; ++q) q0 *= c[q];
            qv[0] = q0;
            float p = c[0];
#pragma unroll
            for (int q = 1; q < QDIM; ++q) { p *= c[q]; qv[q] = p; }

            v2f qp[4];
            qp[0] = (v2f){qv[0], qv[1]};
            qp[1] = (v2f){qv[2], qv[3]};
            qp[2] = (v2f){qv[4], qv[5]};
            qp[3] = (v2f){qv[6], qv[7]};

            // ---- decode (packed over q-pairs) + residual ----
            float oacc[4];
            oacc[0] = xv[i].x; oacc[1] = xv[i].y;
            oacc[2] = xv[i].z; oacc[3] = xv[i].w;
#pragma unroll
            for (int j = 0; j < 4; ++j) {
                v2f a = qp[0] * wdec2[j][0];
                a = __builtin_elementwise_fma(qp[1], wdec2[j][1], a);
                a = __builtin_elementwise_fma(qp[2], wdec2[j][2], a);
                a = __builtin_elementwise_fma(qp[3], wdec2[j][3], a);
                oacc[j] += a.x + a.y;
            }
            v4f o = (v4f){oacc[0], oacc[1], oacc[2], oacc[3]};
            __builtin_nontemporal_store(o, (v4f*)(out + (size_t)(tok0 + it * T + i) * EDIM + e0));
        }

        if (it + 1 < ITERS) {
#pragma unroll
            for (int i = 0; i < T; ++i) xv[i] = xn[i];
        }
    }
}

extern "C" void kernel_launch(void* const* d_in, const int* in_sizes, int n_in,
                              void* d_out, int out_size, void* d_ws, size_t ws_size,
                              hipStream_t stream) {
    const float* x     = (const float*)d_in[0];
    const float* W_enc = (const float*)d_in[1];
    const float* W_dec = (const float*)d_in[2];
    float* out         = (float*)d_out;

    hipLaunchKernelGGL(qattn_kernel, dim3(GRID), dim3(BLOCK), 0, stream,
                       x, W_enc, W_dec, out);
}